// Round 3
// baseline (293.693 us; speedup 1.0000x reference)
//
#include <hip/hip_runtime.h>
#include <hip/hip_bf16.h>
#include <cstdint>

// MultiHeadSelfAttention: B=4, N=2048, C=1024, H=16, D=64
// R12: attn T5 setprio (kept).
// R13 (delta from R12): gemm_qkv rewritten as 256x192-tile / 8-wave / 8-phase
//  counted-vmcnt kernel (T2 xor-swizzle + T3/T4 + T5):
//   - grid 32x16 = 512 blocks = exactly 2 full rounds at 1 block/CU (BN=192
//     chosen so no partial round; 256^2 would give 384 blocks = 75% eff).
//   - LDS 112KB: A[2][256][64] + B[2][192][64] bf16, dbuf per K-tile parity.
//   - 3-bit granule XOR swizzle (g ^= row&7): inverse-swz global source via
//     global_load_lds linear dest + swz ds_read (rule #21).
//   - 8 phases/iter (2 K-tiles), per phase: ds_read subtile | 1-4 stage insts
//     | barrier | lgkmcnt(0) | setprio(1) 16-or-8 MFMA setprio(0) | barrier.
//   - counted vmcnt(4) @P4, vmcnt(3) @P8 (derived: FIFO per-wave, region-safe).
//  attn/prep/gemm_out unchanged for attribution.

typedef __attribute__((ext_vector_type(8))) short short8;    // 8 bf16
typedef __attribute__((ext_vector_type(4))) float floatx4;

#if __has_builtin(__builtin_amdgcn_exp2f)
#define EXP2F(x) __builtin_amdgcn_exp2f(x)
#else
#define EXP2F(x) __expf((x) * 0.6931471805599453f)
#endif

__device__ __forceinline__ unsigned short f2bf(float f) {
  unsigned u = __float_as_uint(f);
  unsigned r = u + 0x7fffu + ((u >> 16) & 1u);   // RNE
  return (unsigned short)(r >> 16);
}

__device__ __forceinline__ void async16(const void* g, void* l) {
  __builtin_amdgcn_global_load_lds(
      (__attribute__((address_space(1))) void*)(void*)(uintptr_t)g,
      (__attribute__((address_space(3))) void*)l, 16, 0, 0);
}

// ------------------------------------------- prep: x cvt + 4x W^T (merged)
__global__ __launch_bounds__(256) void prep_kernel(
    const float* __restrict__ x, unsigned short* __restrict__ xb,
    const float* __restrict__ W0, const float* __restrict__ W1,
    const float* __restrict__ W2, const float* __restrict__ W3,
    unsigned short* __restrict__ T0, unsigned short* __restrict__ T1,
    unsigned short* __restrict__ T2, unsigned short* __restrict__ T3) {
  const int tid = threadIdx.x;
  int blk = blockIdx.x;
  if (blk < 8192) {               // ---- x f32 -> bf16
    int i = (blk * 256 + tid) * 4;
    float4 v = *(const float4*)(x + i);
    ushort4 o;
    o.x = f2bf(v.x); o.y = f2bf(v.y); o.z = f2bf(v.z); o.w = f2bf(v.w);
    *(ushort4*)(xb + i) = o;
  } else {                        // ---- W transpose+convert, 32x32 tiles
    int t = blk - 8192;
    int z = t >> 10, tile = t & 1023;
    const float* W = z == 0 ? W0 : z == 1 ? W1 : z == 2 ? W2 : W3;
    unsigned short* T = z == 0 ? T0 : z == 1 ? T1 : z == 2 ? T2 : T3;
    __shared__ float tb[32][33];
    int tx = tid & 31, ty = tid >> 5;            // 32 x 8
    int bx = (tile & 31) * 32, by = (tile >> 5) * 32;
#pragma unroll
    for (int i = 0; i < 4; ++i)
      tb[ty + i * 8][tx] = W[(size_t)(by + ty + i * 8) * 1024 + bx + tx];
    __syncthreads();
#pragma unroll
    for (int i = 0; i < 4; ++i)
      T[(size_t)(bx + ty + i * 8) * 1024 + by + tx] = f2bf(tb[tx][ty + i * 8]);
  }
}

// ------------------------------------------- fused QKV projection (M x 3072)
// 256x192 tile, 8 waves (2M x 4N), per-wave 128x48 (acc[8][3]).
// LDS: A[2][256 rows][128B] @0, B[2][192 rows][128B] @65536. 112KB total.
__global__ __launch_bounds__(512, 2) void gemm_qkv(
    const unsigned short* __restrict__ A, const unsigned short* __restrict__ BT,
    const float* __restrict__ bq, const float* __restrict__ bk,
    const float* __restrict__ bv,
    unsigned short* __restrict__ Qo, unsigned short* __restrict__ Ko,
    unsigned short* __restrict__ Vo) {
  constexpr int Kd = 1024;
  __shared__ __align__(16) char smem[114688];
  char* const smA = smem;            // [2][256][128B]
  char* const smB = smem + 65536;    // [2][192][128B]

  const int tid = threadIdx.x;
  const int w = tid >> 6, lane = tid & 63;
  const int quad = lane >> 4, l16 = lane & 15;
  const int h = w >> 2;              // A half (0: rows 0-127, 1: 128-255)
  const int wj = w & 3;              // B quarter (48 rows each)

  // XCD-aware swizzle: nwg=512 (512%8==0, bijective)
  int bid = blockIdx.x;
  int lin = (bid & 7) * 64 + (bid >> 3);
  const int m0 = (lin & 31) * 256;
  const int n0 = (lin >> 5) * 192;

  // staging constants: chunk = 64 rows x 128B = 8KB; wave w stages rows
  // c*64 + w*8 + (lane>>3); stored granule (lane&7) holds logical granule
  // (lane&7)^((lane>>3)&7)  [3-bit XOR swizzle, involution]
  const int srow = w * 8 + (lane >> 3);
  const int sgl8 = ((lane & 7) ^ ((lane >> 3) & 7)) * 8;   // element offset
  const unsigned short* Ag = A + (size_t)m0 * Kd;
  const unsigned short* Bg = BT + (size_t)n0 * Kd;

  // frag-read bases: logical granule gl=ks*4+quad stored at gl^(row&7), row&7=l16&7
  const int gx0 = (((0 * 4 + quad) ^ (l16 & 7)) << 4);
  const int gx1 = (((1 * 4 + quad) ^ (l16 & 7)) << 4);
  const int aRB = (h * 128 + l16) * 128;   // + i*2048 + gx
  const int bRB = (wj * 48 + l16) * 128;   // + j*2048 + gx

  floatx4 acc[8][3] = {};
  short8 a[4][2], bfr[3][2];

#define STAGE_A(S, c, ke)                                                     \
  async16(Ag + (size_t)((c) * 64 + srow) * Kd + (ke) + sgl8,                  \
          smA + (S) * 32768 + (c) * 8192 + w * 1024)
#define STAGE_B(S, c, ke)                                                     \
  async16(Bg + (size_t)((c) * 64 + srow) * Kd + (ke) + sgl8,                  \
          smB + (S) * 24576 + (c) * 8192 + w * 1024)
#define RD_A(S, ibase)                                                        \
  { _Pragma("unroll") for (int i = 0; i < 4; ++i) {                           \
      a[i][0] = *(const short8*)(smA + (S) * 32768 + aRB + ((ibase) + i) * 2048 + gx0); \
      a[i][1] = *(const short8*)(smA + (S) * 32768 + aRB + ((ibase) + i) * 2048 + gx1); } }
#define RD_B01(S)                                                             \
  { _Pragma("unroll") for (int j = 0; j < 2; ++j) {                           \
      bfr[j][0] = *(const short8*)(smB + (S) * 24576 + bRB + j * 2048 + gx0); \
      bfr[j][1] = *(const short8*)(smB + (S) * 24576 + bRB + j * 2048 + gx1); } }
#define RD_B2(S)                                                              \
  { bfr[2][0] = *(const short8*)(smB + (S) * 24576 + bRB + 2 * 2048 + gx0);   \
    bfr[2][1] = *(const short8*)(smB + (S) * 24576 + bRB + 2 * 2048 + gx1); }
#define BARRIER __builtin_amdgcn_s_barrier()
#define LGKM0 asm volatile("s_waitcnt lgkmcnt(0)" ::: "memory")
#define PRIO1 __builtin_amdgcn_s_setprio(1)
#define PRIO0 __builtin_amdgcn_s_setprio(0)
// MFMA quadrant: a[0..3] x bfr[J0..JN) -> acc[AOFF..][j]
#define MM(J0, JN, AOFF)                                                      \
  { _Pragma("unroll") for (int i = 0; i < 4; ++i)                             \
      _Pragma("unroll") for (int j = (J0); j < (JN); ++j) {                   \
        acc[i + (AOFF)][j] = __builtin_amdgcn_mfma_f32_16x16x32_bf16(         \
            a[i][0], bfr[j][0], acc[i + (AOFF)][j], 0, 0, 0);                 \
        acc[i + (AOFF)][j] = __builtin_amdgcn_mfma_f32_16x16x32_bf16(         \
            a[i][1], bfr[j][1], acc[i + (AOFF)][j], 0, 0, 0); } }

  // ---- prologue: A(0)->buf0 (4), B(0)->buf0 (3), B(1)->buf1 (3); wait A0,B0
  STAGE_A(0, 0, 0); STAGE_A(0, 1, 0); STAGE_A(0, 2, 0); STAGE_A(0, 3, 0);
  STAGE_B(0, 0, 0); STAGE_B(0, 1, 0); STAGE_B(0, 2, 0);
  STAGE_B(1, 0, 64); STAGE_B(1, 1, 64); STAGE_B(1, 2, 64);
  asm volatile("s_waitcnt vmcnt(3)" ::: "memory");
  BARRIER;

  // ---- main loop: iter t = K-tiles 2t (buf0, P1-P4) and 2t+1 (buf1, P5-P8)
#pragma unroll 1
  for (int t = 0; t < 8; ++t) {
    const int ke0 = t * 128;          // element-k of K-tile 2t
    const bool last = (t == 7);
    // P1: read A[0:4],B[0:2] of buf0; stage A(2t+1) all 4 chunks -> buf1
    RD_A(0, 0); RD_B01(0);
    STAGE_A(1, 0, ke0 + 64); STAGE_A(1, 1, ke0 + 64);
    STAGE_A(1, 2, ke0 + 64); STAGE_A(1, 3, ke0 + 64);
    BARRIER; LGKM0; PRIO1; MM(0, 2, 0); PRIO0; BARRIER;
    // P2: read B[2]
    RD_B2(0);
    BARRIER; LGKM0; PRIO1; MM(2, 3, 0); PRIO0; BARRIER;
    // P3: read A[4:8]; stage B(2t+2) c0,c1 -> buf0
    RD_A(0, 4);
    if (!last) { STAGE_B(0, 0, ke0 + 128); STAGE_B(0, 1, ke0 + 128); }
    BARRIER; LGKM0; PRIO1; MM(2, 3, 4); PRIO0; BARRIER;
    // P4: stage B c2 + A(2t+2) c0 -> buf0; vmcnt
    if (!last) { STAGE_B(0, 2, ke0 + 128); STAGE_A(0, 0, ke0 + 128); }
    BARRIER; LGKM0; PRIO1; MM(0, 2, 4); PRIO0;
    if (!last) { asm volatile("s_waitcnt vmcnt(4)" ::: "memory"); }
    else       { asm volatile("s_waitcnt vmcnt(0)" ::: "memory"); }
    BARRIER;
    // P5: read A[0:4],B[0:2] of buf1; stage A(2t+2) c2
    RD_A(1, 0); RD_B01(1);
    if (!last) { STAGE_A(0, 2, ke0 + 128); }
    BARRIER; LGKM0; PRIO1; MM(0, 2, 0); PRIO0; BARRIER;
    // P6: read B[2]; stage A(2t+2) c1,c3
    RD_B2(1);
    if (!last) { STAGE_A(0, 1, ke0 + 128); STAGE_A(0, 3, ke0 + 128); }
    BARRIER; LGKM0; PRIO1; MM(2, 3, 0); PRIO0; BARRIER;
    // P7: read A[4:8]; stage B(2t+3) c0,c1 -> buf1
    RD_A(1, 4);
    if (!last) { STAGE_B(1, 0, ke0 + 192); STAGE_B(1, 1, ke0 + 192); }
    BARRIER; LGKM0; PRIO1; MM(2, 3, 4); PRIO0; BARRIER;
    // P8: stage B c2; vmcnt(3)
    if (!last) { STAGE_B(1, 2, ke0 + 192); }
    BARRIER; LGKM0; PRIO1; MM(0, 2, 4); PRIO0;
    if (!last) { asm volatile("s_waitcnt vmcnt(3)" ::: "memory"); }
    BARRIER;
  }

#undef STAGE_A
#undef STAGE_B
#undef RD_A
#undef RD_B01
#undef RD_B2
#undef MM

  // ---- epilogue: direct scatter (per-lane mid: 192-col tile can span Q/K/V)
#pragma unroll
  for (int j = 0; j < 3; ++j) {
    int gcol = n0 + wj * 48 + j * 16 + l16;
    int mid = gcol >> 10, cn = gcol & 1023;
    const float* bias = mid == 0 ? bq : mid == 1 ? bk : bv;
    float bb = bias[cn];
    float scale = mid == 0 ? 0.180336880021082f : 1.0f;  // Q: 0.125*log2(e)
    int hh = cn >> 6, d = cn & 63;
#pragma unroll
    for (int i = 0; i < 8; ++i) {
      int rbase = m0 + h * 128 + i * 16 + quad * 4;
#pragma unroll
      for (int r = 0; r < 4; ++r) {
        int row = rbase + r;
        unsigned short hv = f2bf((acc[i][j][r] + bb) * scale);
        int bi = row >> 11, ni = row & 2047;
        size_t bh = (size_t)bi * 16 + hh;
        if (mid == 2) {   // V^T B-frag, key order interleaved
          int nt = d >> 4, vl = d & 15;
          int kq = ni >> 5, jk = ni & 31;
          int pos = ((jk & 15) << 1) | (jk >> 4);
          Vo[((bh * 64 + kq) * 4 + nt) * 512 + (pos >> 3) * 128 + vl * 8 + (pos & 7)] = hv;
        } else {          // Q/K frag
          int kfg = ni >> 4, tl = ni & 15;
          int kk = d >> 5, dq = (d & 31) >> 3, dj = d & 7;
          unsigned short* outp = mid == 0 ? Qo : Ko;
          outp[((bh * 128 + kfg) * 2 + kk) * 512 + dq * 128 + tl * 8 + dj] = hv;
        }
      }
    }
  }
}

// --------------------------------------------------------------- attention
// Block: 4 waves = 2 q-groups (32 rows) x 2 key-halves (32 kt each).
// Grid 2048. No barriers in main loop. P parity double-buffer + K-frag
// register prefetch. R12: setprio(1) around MFMA clusters (T5, m191 regime).
__global__ __launch_bounds__(256, 3) void attn_kernel(
    const unsigned short* __restrict__ Qs, const unsigned short* __restrict__ Ksw,
    const unsigned short* __restrict__ Vsw, unsigned short* __restrict__ O) {
  __shared__ __align__(16) char smem[20480];

  const int tid = threadIdx.x, wave = tid >> 6, lane = tid & 63;
  const int quad = lane >> 4, l16 = lane & 15;
  const int wk = wave & 1, wqi = wave >> 1;
  int blk = blockIdx.x;
  int xcd = blk & 7, slot = blk >> 3;
  int bh = (slot & 7) * 8 + xcd, qb = slot >> 3;   // qb: 0..31 (64-row blocks)

  unsigned short* Pw0 = (unsigned short*)(smem + wave * 5120);
  unsigned short* Pw1 = (unsigned short*)(smem + wave * 5120 + 2560);

  // Q A-frags (2 row-tiles x 2 k-halves)
  short8 aq[2][2];
#pragma unroll
  for (int rt = 0; rt < 2; ++rt)
#pragma unroll
    for (int kk = 0; kk < 2; ++kk)
      aq[rt][kk] = *(const short8*)(Qs +
          (((size_t)bh * 128 + qb * 4 + wqi * 2 + rt) * 2 + kk) * 512 + lane * 8);

  short8 ones;
#pragma unroll
  for (int i = 0; i < 8; ++i) ones[i] = (short)0x3F80;   // bf16 1.0

  const float MSUB = 17.3123404906675611f;   // 12*log2(e); scores in log2 units
  floatx4 mneg;
#pragma unroll
  for (int i = 0; i < 4; ++i) mneg[i] = -MSUB;

  floatx4 acc_o[2][4] = {};
  floatx4 acc_l[2] = {};

  const unsigned short* kptr0 = Ksw + (size_t)bh * 128 * 2 * 512 + (size_t)wk * 32 * 2048;
  const unsigned short* vptr0 = Vsw + (size_t)bh * 64 * 4 * 512 + (size_t)wk * 32 * 2048;

  short8 kf0[2][2], kf1[2][2], vf[4];
  floatx4 sacc[2][2];

#define LOAD_KF(dst, KT)                                                          \
  {                                                                               \
    _Pragma("unroll") for (int ct = 0; ct < 2; ++ct)                              \
        _Pragma("unroll") for (int kk = 0; kk < 2; ++kk)                          \
            dst[ct][kk] = *(const short8*)(kptr0 + (size_t)(KT)*2048 +            \
                                           (ct * 2 + kk) * 512 + lane * 8);       \
  }
#define LOAD_VF(KT)                                                               \
  {                                                                               \
    _Pragma("unroll") for (int nt = 0; nt < 4; ++nt)                              \
        vf[nt] = *(const short8*)(vptr0 + (size_t)(KT)*2048 + nt * 512 + lane * 8); \
  }
#define QK_BLOCK(KF)                                                              \
  {                                                                               \
    __builtin_amdgcn_s_setprio(1);                                                \
    _Pragma("unroll") for (int rt = 0; rt < 2; ++rt)                              \
        _Pragma("unroll") for (int ct = 0; ct < 2; ++ct) {                        \
      sacc[rt][ct] = __builtin_amdgcn_mfma_f32_16x16x32_bf16(aq[rt][0], KF[ct][0], mneg, 0, 0, 0); \
      sacc[rt][ct] = __builtin_amdgcn_mfma_f32_16x16x32_bf16(aq[rt][1], KF[ct][1], sacc[rt][ct], 0, 0, 0); \
    }                                                                             \
    __builtin_amdgcn_s_setprio(0);                                                \
  }
#define EXP_WRITE(PBUF)                                                           \
  {                                                                               \
    _Pragma("unroll") for (int rt = 0; rt < 2; ++rt)                              \
        _Pragma("unroll") for (int r = 0; r < 4; ++r) {                           \
      float pe = EXP2F(sacc[rt][0][r]);                                           \
      float po = EXP2F(sacc[rt][1][r]);                                           \
      unsigned pk = __builtin_amdgcn_perm(__float_as_uint(po), __float_as_uint(pe), 0x07060302u); \
      ((unsigned*)((PBUF) + (rt * 16 + quad * 4 + r) * 40))[l16] = pk;            \
    }                                                                             \
  }
#define PV_BLOCK(PBUF)                                                            \
  {                                                                               \
    __builtin_amdgcn_s_setprio(1);                                                \
    _Pragma("unroll") for (int rt = 0; rt < 2; ++rt) {                            \
      short8 ap = *(const short8*)((PBUF) + (rt * 16 + l16) * 40 + quad * 8);     \
      acc_l[rt] = __builtin_amdgcn_mfma_f32_16x16x32_bf16(ap, ones, acc_l[rt], 0, 0, 0); \
      _Pragma("unroll") for (int nt = 0; nt < 4; ++nt)                            \
          acc_o[rt][nt] = __builtin_amdgcn_mfma_f32_16x16x32_bf16(ap, vf[nt], acc_o[rt][nt], 0, 0, 0); \
    }                                                                             \
    __builtin_amdgcn_s_setprio(0);                                                \
  }

  // ---- prologue: kt=0 (kf0), prefetch kt=1 (kf1), vf=V(0)
  LOAD_KF(kf0, 0);
  LOAD_KF(kf1, 1);
  LOAD_VF(0);
  QK_BLOCK(kf0);
  EXP_WRITE(Pw0);

  // ---- main: i = 2it+1 (odd: cur=kf1, next->kf0, Pprev=Pw0, Pcur=Pw1)
  //            i = 2it+2 (even: cur=kf0, next->kf1, Pprev=Pw1, Pcur=Pw0)
  for (int it = 0; it < 15; ++it) {
    const int i1 = 2 * it + 1, i2 = 2 * it + 2;
    // odd sub-iter
    LOAD_KF(kf0, i1 + 1);
    QK_BLOCK(kf1);
    PV_BLOCK(Pw0);          // PV(i1-1) with vf = V(i1-1)
    LOAD_VF(i1);
    EXP_WRITE(Pw1);
    // even sub-iter
    LOAD_KF(kf1, i2 + 1);
    QK_BLOCK(kf0);
    PV_BLOCK(Pw1);          // PV(i2-1)
    LOAD_VF(i2);
    EXP_WRITE(Pw0);
  }
  // ---- tail: i = 31 (odd roles, no prefetch)
  QK_BLOCK(kf1);
  PV_BLOCK(Pw0);            // PV(30)
  LOAD_VF(31);
  EXP_WRITE(Pw1);
  PV_BLOCK(Pw1);            // PV(31)

#undef LOAD_KF
#undef LOAD_VF
#undef QK_BLOCK
#undef EXP_WRITE
#undef PV_BLOCK

  // ---- combine key halves, normalize, store
  float* buf = (float*)smem + wqi * 2176;          // 32 x 68 f32
  float* lbuf = (float*)(smem + 17408);            // 64 f32
  __syncthreads();
  if (wk == 1) {
#pragma unroll
    for (int rt = 0; rt < 2; ++rt)
#pragma unroll
      for (int r = 0; r < 4; ++r) {
        int row = rt * 16 + quad * 4 + r;
#pragma unroll
        for (int nt = 0; nt < 4; ++nt)
          buf[row * 68 + nt * 16 + l16] = acc_o[rt][nt][r];
        if (l16 == 0) lbuf[wqi * 32 + row] = acc_l[rt][r];
      }
  }
  __syncthreads();
  if (wk == 0) {
    const int b = bh >> 4, h = bh & 15;
#pragma unroll
    for (int rt = 0; rt < 2; ++rt)
#pragma unroll
      for (int r = 0; r < 4; ++r) {
        int row = rt * 16 + quad * 4 + r;
        float linv = 1.0f / (acc_l[rt][r] + lbuf[wqi * 32 + row]);
        int grow = qb * 64 + wqi * 32 + row;
#pragma unroll
        for (int nt = 0; nt < 4; ++nt) {
          float v = (acc_o[rt][nt][r] + buf[row * 68 + nt * 16 + l16]) * linv;
          O[((size_t)b * 2048 + grow) * 1024 + h * 64 + nt * 16 + l16] = f2bf(v);
        }
      }
  }
}

// ------------------------------------------------------------- output GEMM
// BK=64, same staging as R10.
__global__ __launch_bounds__(256) void gemm_out(
    const unsigned short* __restrict__ A, const unsigned short* __restrict__ BT,
    const float* __restrict__ bias, float* __restrict__ of) {
  constexpr int Kd = 1024;
  __shared__ unsigned short As[2 * 128 * 32];
  __shared__ unsigned short Bs[2 * 128 * 32];
  const int tid = threadIdx.x;
  const int wave = tid >> 6, lane = tid & 63;
  const int quad = lane >> 4, l16 = lane & 15;
  const int wm = (wave & 1) * 64, wn = (wave >> 1) * 64;
  const int m0 = blockIdx.x * 128, n0 = blockIdx.y * 128;

  floatx4 acc[4][4] = {};
  const unsigned short* Ag = A + (size_t)m0 * Kd;
  const unsigned short* Bg = BT + (size_t)n0 * Kd;

  for (int k0 = 0; k0 < Kd; k0 += 64) {
    __syncthreads();
#pragma unroll
    for (int p = 0; p < 4; ++p) {
      int c = (wave * 4 + p) * 64 + lane;
      int h = c >> 9, row = (c >> 2) & 127, kp = c & 3;
      async16(Ag + (size_t)row * Kd + k0 + h * 32 + kp * 8, (char*)As + (size_t)(wave * 4 + p) * 1024);
      async16(Bg + (size_t)row * Kd + k0 + h * 32 + kp * 8, (char*)Bs + (size_t)(wave * 4 + p) * 1024);
    }
    __syncthreads();
#pragma unroll
    for (int ks = 0; ks < 2; ++ks) {
      short8 a[4], b[4];
#pragma unroll
      for (int i = 0; i < 4; ++i) {
        a[i] = *(const short8*)(As + ks * 4096 + (wm + i * 16 + l16) * 32 + quad * 8);
        b[i] = *(const short8*)(Bs + ks * 4096 + (wn + i * 16 + l16) * 32 + quad * 8);
      }
#pragma unroll
      for (int i = 0; i < 4; ++i)
#pragma unroll
        for (int j = 0; j < 4; ++j)
          acc[i][j] = __builtin_amdgcn_mfma_f32_16x16x32_bf16(a[i], b[j], acc[i][j], 0, 0, 0);
    }
  }

#pragma unroll
  for (int j = 0; j < 4; ++j) {
    int col = n0 + wn + j * 16 + l16;
    float bb = bias[col];
#pragma unroll
    for (int i = 0; i < 4; ++i) {
      int rbase = m0 + wm + i * 16 + quad * 4;
#pragma unroll
      for (int r = 0; r < 4; ++r)
        of[(size_t)(rbase + r) * 1024 + col] = acc[i][j][r] + bb;
    }
  }
}

// ---------------------------------------------------------------- launch
extern "C" void kernel_launch(void* const* d_in, const int* in_sizes, int n_in,
                              void* d_out, int out_size, void* d_ws, size_t ws_size,
                              hipStream_t stream) {
  const float* x  = (const float*)d_in[0];
  const float* Wq = (const float*)d_in[1];
  const float* bq = (const float*)d_in[2];
  const float* Wk = (const float*)d_in[3];
  const float* bk = (const float*)d_in[4];
  const float* Wv = (const float*)d_in[5];
  const float* bv = (const float*)d_in[6];
  const float* Wo = (const float*)d_in[7];
  const float* bo = (const float*)d_in[8];

  char* ws = (char*)d_ws;
  unsigned short* xb  = (unsigned short*)(ws);                 // 16 MiB
  unsigned short* wqt = (unsigned short*)(ws + (16u << 20));   // 2 MiB each, contiguous
  unsigned short* wkt = (unsigned short*)(ws + (18u << 20));
  unsigned short* wvt = (unsigned short*)(ws + (20u << 20));
  unsigned short* wot = (unsigned short*)(ws + (22u << 20));
  unsigned short* Qb  = (unsigned short*)(ws + (24u << 20));   // 16 MiB each
  unsigned short* Kb  = (unsigned short*)(ws + (40u << 20));
  unsigned short* Vtb = (unsigned short*)(ws + (56u << 20));
  unsigned short* Ob  = (unsigned short*)(ws + (72u << 20));   // total 88 MiB

  prep_kernel<<<dim3(12288), 256, 0, stream>>>(x, xb, Wq, Wk, Wv, Wo, wqt, wkt, wvt, wot);
  gemm_qkv<<<dim3(512), 512, 0, stream>>>(xb, wqt, bq, bk, bv, Qb, Kb, Vtb);
  attn_kernel<<<dim3(2048), 256, 0, stream>>>(Qb, Kb, Vtb, Ob);
  gemm_out<<<dim3(64, 8), 256, 0, stream>>>(Ob, wot, bo, (float*)d_out);
}

// Round 4
// 279.715 us; speedup vs baseline: 1.0500x; 1.0500x over previous
//
#include <hip/hip_runtime.h>
#include <hip/hip_bf16.h>
#include <cstdint>

// MultiHeadSelfAttention: B=4, N=2048, C=1024, H=16, D=64
// R12: attn T5 setprio (kept).
// R13: gemm_qkv 256x192 / 8-wave / 8-phase counted-vmcnt (T2+T3/T4+T5).
//  Result: 87.5us unchanged vs 2-phase; conflicts 0, VALU halved, but
//  FETCH 49->134MB: old XCD map put all 32 m-tiles concurrently on one XCD
//  (A WS 16.8MB >> 4MB L2) -> every A stage L2-missed -> staging-BW bound.
// R14 (delta from R13): gemm_qkv block map only. Each XCD's 32 concurrent
//  blocks = 4m x 8n cohort (A WS 2MB L2-fits, A-tile shared by 8 blocks,
//  B-tile by 4; round 2 reuses same m-group). m=x*4+(s&3), n=r*8+(s>>2).

typedef __attribute__((ext_vector_type(8))) short short8;    // 8 bf16
typedef __attribute__((ext_vector_type(4))) float floatx4;

#if __has_builtin(__builtin_amdgcn_exp2f)
#define EXP2F(x) __builtin_amdgcn_exp2f(x)
#else
#define EXP2F(x) __expf((x) * 0.6931471805599453f)
#endif

__device__ __forceinline__ unsigned short f2bf(float f) {
  unsigned u = __float_as_uint(f);
  unsigned r = u + 0x7fffu + ((u >> 16) & 1u);   // RNE
  return (unsigned short)(r >> 16);
}

__device__ __forceinline__ void async16(const void* g, void* l) {
  __builtin_amdgcn_global_load_lds(
      (__attribute__((address_space(1))) void*)(void*)(uintptr_t)g,
      (__attribute__((address_space(3))) void*)l, 16, 0, 0);
}

// ------------------------------------------- prep: x cvt + 4x W^T (merged)
__global__ __launch_bounds__(256) void prep_kernel(
    const float* __restrict__ x, unsigned short* __restrict__ xb,
    const float* __restrict__ W0, const float* __restrict__ W1,
    const float* __restrict__ W2, const float* __restrict__ W3,
    unsigned short* __restrict__ T0, unsigned short* __restrict__ T1,
    unsigned short* __restrict__ T2, unsigned short* __restrict__ T3) {
  const int tid = threadIdx.x;
  int blk = blockIdx.x;
  if (blk < 8192) {               // ---- x f32 -> bf16
    int i = (blk * 256 + tid) * 4;
    float4 v = *(const float4*)(x + i);
    ushort4 o;
    o.x = f2bf(v.x); o.y = f2bf(v.y); o.z = f2bf(v.z); o.w = f2bf(v.w);
    *(ushort4*)(xb + i) = o;
  } else {                        // ---- W transpose+convert, 32x32 tiles
    int t = blk - 8192;
    int z = t >> 10, tile = t & 1023;
    const float* W = z == 0 ? W0 : z == 1 ? W1 : z == 2 ? W2 : W3;
    unsigned short* T = z == 0 ? T0 : z == 1 ? T1 : z == 2 ? T2 : T3;
    __shared__ float tb[32][33];
    int tx = tid & 31, ty = tid >> 5;            // 32 x 8
    int bx = (tile & 31) * 32, by = (tile >> 5) * 32;
#pragma unroll
    for (int i = 0; i < 4; ++i)
      tb[ty + i * 8][tx] = W[(size_t)(by + ty + i * 8) * 1024 + bx + tx];
    __syncthreads();
#pragma unroll
    for (int i = 0; i < 4; ++i)
      T[(size_t)(bx + ty + i * 8) * 1024 + by + tx] = f2bf(tb[tx][ty + i * 8]);
  }
}

// ------------------------------------------- fused QKV projection (M x 3072)
// 256x192 tile, 8 waves (2M x 4N), per-wave 128x48 (acc[8][3]).
// LDS: A[2][256 rows][128B] @0, B[2][192 rows][128B] @65536. 112KB total.
__global__ __launch_bounds__(512, 2) void gemm_qkv(
    const unsigned short* __restrict__ A, const unsigned short* __restrict__ BT,
    const float* __restrict__ bq, const float* __restrict__ bk,
    const float* __restrict__ bv,
    unsigned short* __restrict__ Qo, unsigned short* __restrict__ Ko,
    unsigned short* __restrict__ Vo) {
  constexpr int Kd = 1024;
  __shared__ __align__(16) char smem[114688];
  char* const smA = smem;            // [2][256][128B]
  char* const smB = smem + 65536;    // [2][192][128B]

  const int tid = threadIdx.x;
  const int w = tid >> 6, lane = tid & 63;
  const int quad = lane >> 4, l16 = lane & 15;
  const int h = w >> 2;              // A half (0: rows 0-127, 1: 128-255)
  const int wj = w & 3;              // B quarter (48 rows each)

  // R14 XCD-cohort map: xcd x, slot s (0..31), round r (0..1).
  // Concurrent per XCD: 4 m-tiles x 8 n-tiles (A WS 2MB fits L2; A shared
  // by 8 blocks, B by 4; round 1 reuses same m-group).
  int bid = blockIdx.x;
  int xh = bid & 7, s = (bid >> 3) & 31, r = bid >> 8;
  const int m0 = (xh * 4 + (s & 3)) * 256;
  const int n0 = (r * 8 + (s >> 2)) * 192;

  // staging constants: chunk = 64 rows x 128B = 8KB; wave w stages rows
  // c*64 + w*8 + (lane>>3); stored granule (lane&7) holds logical granule
  // (lane&7)^((lane>>3)&7)  [3-bit XOR swizzle, involution]
  const int srow = w * 8 + (lane >> 3);
  const int sgl8 = ((lane & 7) ^ ((lane >> 3) & 7)) * 8;   // element offset
  const unsigned short* Ag = A + (size_t)m0 * Kd;
  const unsigned short* Bg = BT + (size_t)n0 * Kd;

  // frag-read bases: logical granule gl=ks*4+quad stored at gl^(row&7), row&7=l16&7
  const int gx0 = (((0 * 4 + quad) ^ (l16 & 7)) << 4);
  const int gx1 = (((1 * 4 + quad) ^ (l16 & 7)) << 4);
  const int aRB = (h * 128 + l16) * 128;   // + i*2048 + gx
  const int bRB = (wj * 48 + l16) * 128;   // + j*2048 + gx

  floatx4 acc[8][3] = {};
  short8 a[4][2], bfr[3][2];

#define STAGE_A(S, c, ke)                                                     \
  async16(Ag + (size_t)((c) * 64 + srow) * Kd + (ke) + sgl8,                  \
          smA + (S) * 32768 + (c) * 8192 + w * 1024)
#define STAGE_B(S, c, ke)                                                     \
  async16(Bg + (size_t)((c) * 64 + srow) * Kd + (ke) + sgl8,                  \
          smB + (S) * 24576 + (c) * 8192 + w * 1024)
#define RD_A(S, ibase)                                                        \
  { _Pragma("unroll") for (int i = 0; i < 4; ++i) {                           \
      a[i][0] = *(const short8*)(smA + (S) * 32768 + aRB + ((ibase) + i) * 2048 + gx0); \
      a[i][1] = *(const short8*)(smA + (S) * 32768 + aRB + ((ibase) + i) * 2048 + gx1); } }
#define RD_B01(S)                                                             \
  { _Pragma("unroll") for (int j = 0; j < 2; ++j) {                           \
      bfr[j][0] = *(const short8*)(smB + (S) * 24576 + bRB + j * 2048 + gx0); \
      bfr[j][1] = *(const short8*)(smB + (S) * 24576 + bRB + j * 2048 + gx1); } }
#define RD_B2(S)                                                              \
  { bfr[2][0] = *(const short8*)(smB + (S) * 24576 + bRB + 2 * 2048 + gx0);   \
    bfr[2][1] = *(const short8*)(smB + (S) * 24576 + bRB + 2 * 2048 + gx1); }
#define BARRIER __builtin_amdgcn_s_barrier()
#define LGKM0 asm volatile("s_waitcnt lgkmcnt(0)" ::: "memory")
#define PRIO1 __builtin_amdgcn_s_setprio(1)
#define PRIO0 __builtin_amdgcn_s_setprio(0)
// MFMA quadrant: a[0..3] x bfr[J0..JN) -> acc[AOFF..][j]
#define MM(J0, JN, AOFF)                                                      \
  { _Pragma("unroll") for (int i = 0; i < 4; ++i)                             \
      _Pragma("unroll") for (int j = (J0); j < (JN); ++j) {                   \
        acc[i + (AOFF)][j] = __builtin_amdgcn_mfma_f32_16x16x32_bf16(         \
            a[i][0], bfr[j][0], acc[i + (AOFF)][j], 0, 0, 0);                 \
        acc[i + (AOFF)][j] = __builtin_amdgcn_mfma_f32_16x16x32_bf16(         \
            a[i][1], bfr[j][1], acc[i + (AOFF)][j], 0, 0, 0); } }

  // ---- prologue: A(0)->buf0 (4), B(0)->buf0 (3), B(1)->buf1 (3); wait A0,B0
  STAGE_A(0, 0, 0); STAGE_A(0, 1, 0); STAGE_A(0, 2, 0); STAGE_A(0, 3, 0);
  STAGE_B(0, 0, 0); STAGE_B(0, 1, 0); STAGE_B(0, 2, 0);
  STAGE_B(1, 0, 64); STAGE_B(1, 1, 64); STAGE_B(1, 2, 64);
  asm volatile("s_waitcnt vmcnt(3)" ::: "memory");
  BARRIER;

  // ---- main loop: iter t = K-tiles 2t (buf0, P1-P4) and 2t+1 (buf1, P5-P8)
#pragma unroll 1
  for (int t = 0; t < 8; ++t) {
    const int ke0 = t * 128;          // element-k of K-tile 2t
    const bool last = (t == 7);
    // P1: read A[0:4],B[0:2] of buf0; stage A(2t+1) all 4 chunks -> buf1
    RD_A(0, 0); RD_B01(0);
    STAGE_A(1, 0, ke0 + 64); STAGE_A(1, 1, ke0 + 64);
    STAGE_A(1, 2, ke0 + 64); STAGE_A(1, 3, ke0 + 64);
    BARRIER; LGKM0; PRIO1; MM(0, 2, 0); PRIO0; BARRIER;
    // P2: read B[2]
    RD_B2(0);
    BARRIER; LGKM0; PRIO1; MM(2, 3, 0); PRIO0; BARRIER;
    // P3: read A[4:8]; stage B(2t+2) c0,c1 -> buf0
    RD_A(0, 4);
    if (!last) { STAGE_B(0, 0, ke0 + 128); STAGE_B(0, 1, ke0 + 128); }
    BARRIER; LGKM0; PRIO1; MM(2, 3, 4); PRIO0; BARRIER;
    // P4: stage B c2 + A(2t+2) c0 -> buf0; vmcnt
    if (!last) { STAGE_B(0, 2, ke0 + 128); STAGE_A(0, 0, ke0 + 128); }
    BARRIER; LGKM0; PRIO1; MM(0, 2, 4); PRIO0;
    if (!last) { asm volatile("s_waitcnt vmcnt(4)" ::: "memory"); }
    else       { asm volatile("s_waitcnt vmcnt(0)" ::: "memory"); }
    BARRIER;
    // P5: read A[0:4],B[0:2] of buf1; stage A(2t+2) c2
    RD_A(1, 0); RD_B01(1);
    if (!last) { STAGE_A(0, 2, ke0 + 128); }
    BARRIER; LGKM0; PRIO1; MM(0, 2, 0); PRIO0; BARRIER;
    // P6: read B[2]; stage A(2t+2) c1,c3
    RD_B2(1);
    if (!last) { STAGE_A(0, 1, ke0 + 128); STAGE_A(0, 3, ke0 + 128); }
    BARRIER; LGKM0; PRIO1; MM(2, 3, 0); PRIO0; BARRIER;
    // P7: read A[4:8]; stage B(2t+3) c0,c1 -> buf1
    RD_A(1, 4);
    if (!last) { STAGE_B(1, 0, ke0 + 192); STAGE_B(1, 1, ke0 + 192); }
    BARRIER; LGKM0; PRIO1; MM(2, 3, 4); PRIO0; BARRIER;
    // P8: stage B c2; vmcnt(3)
    if (!last) { STAGE_B(1, 2, ke0 + 192); }
    BARRIER; LGKM0; PRIO1; MM(0, 2, 4); PRIO0;
    if (!last) { asm volatile("s_waitcnt vmcnt(3)" ::: "memory"); }
    BARRIER;
  }

#undef STAGE_A
#undef STAGE_B
#undef RD_A
#undef RD_B01
#undef RD_B2
#undef MM

  // ---- epilogue: direct scatter (per-lane mid: 192-col tile can span Q/K/V)
#pragma unroll
  for (int j = 0; j < 3; ++j) {
    int gcol = n0 + wj * 48 + j * 16 + l16;
    int mid = gcol >> 10, cn = gcol & 1023;
    const float* bias = mid == 0 ? bq : mid == 1 ? bk : bv;
    float bb = bias[cn];
    float scale = mid == 0 ? 0.180336880021082f : 1.0f;  // Q: 0.125*log2(e)
    int hh = cn >> 6, d = cn & 63;
#pragma unroll
    for (int i = 0; i < 8; ++i) {
      int rbase = m0 + h * 128 + i * 16 + quad * 4;
#pragma unroll
      for (int r2 = 0; r2 < 4; ++r2) {
        int row = rbase + r2;
        unsigned short hv = f2bf((acc[i][j][r2] + bb) * scale);
        int bi = row >> 11, ni = row & 2047;
        size_t bh = (size_t)bi * 16 + hh;
        if (mid == 2) {   // V^T B-frag, key order interleaved
          int nt = d >> 4, vl = d & 15;
          int kq = ni >> 5, jk = ni & 31;
          int pos = ((jk & 15) << 1) | (jk >> 4);
          Vo[((bh * 64 + kq) * 4 + nt) * 512 + (pos >> 3) * 128 + vl * 8 + (pos & 7)] = hv;
        } else {          // Q/K frag
          int kfg = ni >> 4, tl = ni & 15;
          int kk = d >> 5, dq = (d & 31) >> 3, dj = d & 7;
          unsigned short* outp = mid == 0 ? Qo : Ko;
          outp[((bh * 128 + kfg) * 2 + kk) * 512 + dq * 128 + tl * 8 + dj] = hv;
        }
      }
    }
  }
}

// --------------------------------------------------------------- attention
// Block: 4 waves = 2 q-groups (32 rows) x 2 key-halves (32 kt each).
// Grid 2048. No barriers in main loop. P parity double-buffer + K-frag
// register prefetch. R12: setprio(1) around MFMA clusters (T5, m191 regime).
__global__ __launch_bounds__(256, 3) void attn_kernel(
    const unsigned short* __restrict__ Qs, const unsigned short* __restrict__ Ksw,
    const unsigned short* __restrict__ Vsw, unsigned short* __restrict__ O) {
  __shared__ __align__(16) char smem[20480];

  const int tid = threadIdx.x, wave = tid >> 6, lane = tid & 63;
  const int quad = lane >> 4, l16 = lane & 15;
  const int wk = wave & 1, wqi = wave >> 1;
  int blk = blockIdx.x;
  int xcd = blk & 7, slot = blk >> 3;
  int bh = (slot & 7) * 8 + xcd, qb = slot >> 3;   // qb: 0..31 (64-row blocks)

  unsigned short* Pw0 = (unsigned short*)(smem + wave * 5120);
  unsigned short* Pw1 = (unsigned short*)(smem + wave * 5120 + 2560);

  // Q A-frags (2 row-tiles x 2 k-halves)
  short8 aq[2][2];
#pragma unroll
  for (int rt = 0; rt < 2; ++rt)
#pragma unroll
    for (int kk = 0; kk < 2; ++kk)
      aq[rt][kk] = *(const short8*)(Qs +
          (((size_t)bh * 128 + qb * 4 + wqi * 2 + rt) * 2 + kk) * 512 + lane * 8);

  short8 ones;
#pragma unroll
  for (int i = 0; i < 8; ++i) ones[i] = (short)0x3F80;   // bf16 1.0

  const float MSUB = 17.3123404906675611f;   // 12*log2(e); scores in log2 units
  floatx4 mneg;
#pragma unroll
  for (int i = 0; i < 4; ++i) mneg[i] = -MSUB;

  floatx4 acc_o[2][4] = {};
  floatx4 acc_l[2] = {};

  const unsigned short* kptr0 = Ksw + (size_t)bh * 128 * 2 * 512 + (size_t)wk * 32 * 2048;
  const unsigned short* vptr0 = Vsw + (size_t)bh * 64 * 4 * 512 + (size_t)wk * 32 * 2048;

  short8 kf0[2][2], kf1[2][2], vf[4];
  floatx4 sacc[2][2];

#define LOAD_KF(dst, KT)                                                          \
  {                                                                               \
    _Pragma("unroll") for (int ct = 0; ct < 2; ++ct)                              \
        _Pragma("unroll") for (int kk = 0; kk < 2; ++kk)                          \
            dst[ct][kk] = *(const short8*)(kptr0 + (size_t)(KT)*2048 +            \
                                           (ct * 2 + kk) * 512 + lane * 8);       \
  }
#define LOAD_VF(KT)                                                               \
  {                                                                               \
    _Pragma("unroll") for (int nt = 0; nt < 4; ++nt)                              \
        vf[nt] = *(const short8*)(vptr0 + (size_t)(KT)*2048 + nt * 512 + lane * 8); \
  }
#define QK_BLOCK(KF)                                                              \
  {                                                                               \
    __builtin_amdgcn_s_setprio(1);                                                \
    _Pragma("unroll") for (int rt = 0; rt < 2; ++rt)                              \
        _Pragma("unroll") for (int ct = 0; ct < 2; ++ct) {                        \
      sacc[rt][ct] = __builtin_amdgcn_mfma_f32_16x16x32_bf16(aq[rt][0], KF[ct][0], mneg, 0, 0, 0); \
      sacc[rt][ct] = __builtin_amdgcn_mfma_f32_16x16x32_bf16(aq[rt][1], KF[ct][1], sacc[rt][ct], 0, 0, 0); \
    }                                                                             \
    __builtin_amdgcn_s_setprio(0);                                                \
  }
#define EXP_WRITE(PBUF)                                                           \
  {                                                                               \
    _Pragma("unroll") for (int rt = 0; rt < 2; ++rt)                              \
        _Pragma("unroll") for (int r = 0; r < 4; ++r) {                           \
      float pe = EXP2F(sacc[rt][0][r]);                                           \
      float po = EXP2F(sacc[rt][1][r]);                                           \
      unsigned pk = __builtin_amdgcn_perm(__float_as_uint(po), __float_as_uint(pe), 0x07060302u); \
      ((unsigned*)((PBUF) + (rt * 16 + quad * 4 + r) * 40))[l16] = pk;            \
    }                                                                             \
  }
#define PV_BLOCK(PBUF)                                                            \
  {                                                                               \
    __builtin_amdgcn_s_setprio(1);                                                \
    _Pragma("unroll") for (int rt = 0; rt < 2; ++rt) {                            \
      short8 ap = *(const short8*)((PBUF) + (rt * 16 + l16) * 40 + quad * 8);     \
      acc_l[rt] = __builtin_amdgcn_mfma_f32_16x16x32_bf16(ap, ones, acc_l[rt], 0, 0, 0); \
      _Pragma("unroll") for (int nt = 0; nt < 4; ++nt)                            \
          acc_o[rt][nt] = __builtin_amdgcn_mfma_f32_16x16x32_bf16(ap, vf[nt], acc_o[rt][nt], 0, 0, 0); \
    }                                                                             \
    __builtin_amdgcn_s_setprio(0);                                                \
  }

  // ---- prologue: kt=0 (kf0), prefetch kt=1 (kf1), vf=V(0)
  LOAD_KF(kf0, 0);
  LOAD_KF(kf1, 1);
  LOAD_VF(0);
  QK_BLOCK(kf0);
  EXP_WRITE(Pw0);

  // ---- main: i = 2it+1 (odd: cur=kf1, next->kf0, Pprev=Pw0, Pcur=Pw1)
  //            i = 2it+2 (even: cur=kf0, next->kf1, Pprev=Pw1, Pcur=Pw0)
  for (int it = 0; it < 15; ++it) {
    const int i1 = 2 * it + 1, i2 = 2 * it + 2;
    // odd sub-iter
    LOAD_KF(kf0, i1 + 1);
    QK_BLOCK(kf1);
    PV_BLOCK(Pw0);          // PV(i1-1) with vf = V(i1-1)
    LOAD_VF(i1);
    EXP_WRITE(Pw1);
    // even sub-iter
    LOAD_KF(kf1, i2 + 1);
    QK_BLOCK(kf0);
    PV_BLOCK(Pw1);          // PV(i2-1)
    LOAD_VF(i2);
    EXP_WRITE(Pw0);
  }
  // ---- tail: i = 31 (odd roles, no prefetch)
  QK_BLOCK(kf1);
  PV_BLOCK(Pw0);            // PV(30)
  LOAD_VF(31);
  EXP_WRITE(Pw1);
  PV_BLOCK(Pw1);            // PV(31)

#undef LOAD_KF
#undef LOAD_VF
#undef QK_BLOCK
#undef EXP_WRITE
#undef PV_BLOCK

  // ---- combine key halves, normalize, store
  float* buf = (float*)smem + wqi * 2176;          // 32 x 68 f32
  float* lbuf = (float*)(smem + 17408);            // 64 f32
  __syncthreads();
  if (wk == 1) {
#pragma unroll
    for (int rt = 0; rt < 2; ++rt)
#pragma unroll
      for (int r = 0; r < 4; ++r) {
        int row = rt * 16 + quad * 4 + r;
#pragma unroll
        for (int nt = 0; nt < 4; ++nt)
          buf[row * 68 + nt * 16 + l16] = acc_o[rt][nt][r];
        if (l16 == 0) lbuf[wqi * 32 + row] = acc_l[rt][r];
      }
  }
  __syncthreads();
  if (wk == 0) {
    const int b = bh >> 4, h = bh & 15;
#pragma unroll
    for (int rt = 0; rt < 2; ++rt)
#pragma unroll
      for (int r = 0; r < 4; ++r) {
        int row = rt * 16 + quad * 4 + r;
        float linv = 1.0f / (acc_l[rt][r] + lbuf[wqi * 32 + row]);
        int grow = qb * 64 + wqi * 32 + row;
#pragma unroll
        for (int nt = 0; nt < 4; ++nt) {
          float v = (acc_o[rt][nt][r] + buf[row * 68 + nt * 16 + l16]) * linv;
          O[((size_t)b * 2048 + grow) * 1024 + h * 64 + nt * 16 + l16] = f2bf(v);
        }
      }
  }
}

// ------------------------------------------------------------- output GEMM
// BK=64, same staging as R10.
__global__ __launch_bounds__(256) void gemm_out(
    const unsigned short* __restrict__ A, const unsigned short* __restrict__ BT,
    const float* __restrict__ bias, float* __restrict__ of) {
  constexpr int Kd = 1024;
  __shared__ unsigned short As[2 * 128 * 32];
  __shared__ unsigned short Bs[2 * 128 * 32];
  const int tid = threadIdx.x;
  const int wave = tid >> 6, lane = tid & 63;
  const int quad = lane >> 4, l16 = lane & 15;
  const int wm = (wave & 1) * 64, wn = (wave >> 1) * 64;
  const int m0 = blockIdx.x * 128, n0 = blockIdx.y * 128;

  floatx4 acc[4][4] = {};
  const unsigned short* Ag = A + (size_t)m0 * Kd;
  const unsigned short* Bg = BT + (size_t)n0 * Kd;

  for (int k0 = 0; k0 < Kd; k0 += 64) {
    __syncthreads();
#pragma unroll
    for (int p = 0; p < 4; ++p) {
      int c = (wave * 4 + p) * 64 + lane;
      int h = c >> 9, row = (c >> 2) & 127, kp = c & 3;
      async16(Ag + (size_t)row * Kd + k0 + h * 32 + kp * 8, (char*)As + (size_t)(wave * 4 + p) * 1024);
      async16(Bg + (size_t)row * Kd + k0 + h * 32 + kp * 8, (char*)Bs + (size_t)(wave * 4 + p) * 1024);
    }
    __syncthreads();
#pragma unroll
    for (int ks = 0; ks < 2; ++ks) {
      short8 a[4], b[4];
#pragma unroll
      for (int i = 0; i < 4; ++i) {
        a[i] = *(const short8*)(As + ks * 4096 + (wm + i * 16 + l16) * 32 + quad * 8);
        b[i] = *(const short8*)(Bs + ks * 4096 + (wn + i * 16 + l16) * 32 + quad * 8);
      }
#pragma unroll
      for (int i = 0; i < 4; ++i)
#pragma unroll
        for (int j = 0; j < 4; ++j)
          acc[i][j] = __builtin_amdgcn_mfma_f32_16x16x32_bf16(a[i], b[j], acc[i][j], 0, 0, 0);
    }
  }

#pragma unroll
  for (int j = 0; j < 4; ++j) {
    int col = n0 + wn + j * 16 + l16;
    float bb = bias[col];
#pragma unroll
    for (int i = 0; i < 4; ++i) {
      int rbase = m0 + wm + i * 16 + quad * 4;
#pragma unroll
      for (int r = 0; r < 4; ++r)
        of[(size_t)(rbase + r) * 1024 + col] = acc[i][j][r] + bb;
    }
  }
}

// ---------------------------------------------------------------- launch
extern "C" void kernel_launch(void* const* d_in, const int* in_sizes, int n_in,
                              void* d_out, int out_size, void* d_ws, size_t ws_size,
                              hipStream_t stream) {
  const float* x  = (const float*)d_in[0];
  const float* Wq = (const float*)d_in[1];
  const float* bq = (const float*)d_in[2];
  const float* Wk = (const float*)d_in[3];
  const float* bk = (const float*)d_in[4];
  const float* Wv = (const float*)d_in[5];
  const float* bv = (const float*)d_in[6];
  const float* Wo = (const float*)d_in[7];
  const float* bo = (const float*)d_in[8];

  char* ws = (char*)d_ws;
  unsigned short* xb  = (unsigned short*)(ws);                 // 16 MiB
  unsigned short* wqt = (unsigned short*)(ws + (16u << 20));   // 2 MiB each, contiguous
  unsigned short* wkt = (unsigned short*)(ws + (18u << 20));
  unsigned short* wvt = (unsigned short*)(ws + (20u << 20));
  unsigned short* wot = (unsigned short*)(ws + (22u << 20));
  unsigned short* Qb  = (unsigned short*)(ws + (24u << 20));   // 16 MiB each
  unsigned short* Kb  = (unsigned short*)(ws + (40u << 20));
  unsigned short* Vtb = (unsigned short*)(ws + (56u << 20));
  unsigned short* Ob  = (unsigned short*)(ws + (72u << 20));   // total 88 MiB

  prep_kernel<<<dim3(12288), 256, 0, stream>>>(x, xb, Wq, Wk, Wv, Wo, wqt, wkt, wvt, wot);
  gemm_qkv<<<dim3(512), 512, 0, stream>>>(xb, wqt, bq, bk, bv, Qb, Kb, Vtb);
  attn_kernel<<<dim3(2048), 256, 0, stream>>>(Qb, Kb, Vtb, Ob);
  gemm_out<<<dim3(64, 8), 256, 0, stream>>>(Ob, wot, bo, (float*)d_out);
}